// Round 1
// baseline (2908.084 us; speedup 1.0000x reference)
//
#include <hip/hip_runtime.h>

constexpr int F_IN  = 256;
constexpr int F_OUT = 128;

#define BM 64
#define BK 32

// ---------------------------------------------------------------------------
// Stage 1: h = x @ W   (fp32, LDS-tiled, 64x128 block tile, 8x4 per thread)
// ---------------------------------------------------------------------------
__global__ __launch_bounds__(256) void gemm_h_kernel(
    const float* __restrict__ x, const float* __restrict__ W,
    float* __restrict__ h, int n_nodes)
{
    // row stride 36 (pad to multiple of 4 for aligned float4 LDS ops)
    __shared__ float As[BM][BK + 4];      // 64 x 36
    __shared__ float Bs[BK][F_OUT + 4];   // 32 x 132

    const int tid  = threadIdx.x;
    const int row0 = blockIdx.x * BM;
    const int trow = tid >> 5;            // 0..7  -> 8 rows each
    const int tcol = tid & 31;            // 0..31 -> 4 cols each

    float acc[8][4];
    #pragma unroll
    for (int i = 0; i < 8; ++i)
        #pragma unroll
        for (int j = 0; j < 4; ++j) acc[i][j] = 0.f;

    const int a_r = tid >> 3;             // 0..31
    const int a_c = (tid & 7) * 4;        // 0..28
    const int b_r = tid >> 5;             // 0..7
    const int b_c = (tid & 31) * 4;       // 0..124

    for (int kt = 0; kt < F_IN; kt += BK) {
        // A tile: 64 rows x 32 cols, 2 passes of 32 rows
        #pragma unroll
        for (int p = 0; p < 2; ++p) {
            int r = a_r + p * 32;
            int grow = row0 + r;
            float4 v = make_float4(0.f, 0.f, 0.f, 0.f);
            if (grow < n_nodes)
                v = *(const float4*)&x[(long long)grow * F_IN + kt + a_c];
            *(float4*)&As[r][a_c] = v;
        }
        // B tile: 32 rows x 128 cols, 4 passes of 8 rows
        #pragma unroll
        for (int p = 0; p < 4; ++p) {
            int r = b_r + p * 8;
            float4 v = *(const float4*)&W[(kt + r) * F_OUT + b_c];
            *(float4*)&Bs[r][b_c] = v;
        }
        __syncthreads();

        #pragma unroll
        for (int k = 0; k < BK; ++k) {
            float4 b = *(float4*)&Bs[k][tcol * 4];
            #pragma unroll
            for (int i = 0; i < 8; ++i) {
                float a = As[trow * 8 + i][k];
                acc[i][0] += a * b.x;
                acc[i][1] += a * b.y;
                acc[i][2] += a * b.z;
                acc[i][3] += a * b.w;
            }
        }
        __syncthreads();
    }

    #pragma unroll
    for (int i = 0; i < 8; ++i) {
        int grow = row0 + trow * 8 + i;
        if (grow < n_nodes) {
            float4 v = make_float4(acc[i][0], acc[i][1], acc[i][2], acc[i][3]);
            *(float4*)&h[(long long)grow * F_OUT + tcol * 4] = v;
        }
    }
}

// ---------------------------------------------------------------------------
// Stage 2: out[n][f] = bias[f]   (harness poisons d_out with 0xAA every call)
// ---------------------------------------------------------------------------
__global__ void init_out_kernel(float* __restrict__ out,
                                const float* __restrict__ bias, int total4)
{
    int i = blockIdx.x * blockDim.x + threadIdx.x;
    if (i < total4) {
        int f = (i * 4) & (F_OUT - 1);
        float4 b = *(const float4*)&bias[f];
        ((float4*)out)[i] = b;
    }
}

// ---------------------------------------------------------------------------
// Stage 3: out[dst] += val * h[src]  — one thread per (edge, 4 features)
// ---------------------------------------------------------------------------
__global__ __launch_bounds__(256) void scatter_kernel(
    const float* __restrict__ h, const int* __restrict__ src,
    const int* __restrict__ dst, const float* __restrict__ vals,
    float* __restrict__ out, int total)   // total = n_edges * 32
{
    int i = blockIdx.x * blockDim.x + threadIdx.x;
    if (i >= total) return;
    int e = i >> 5;
    int f = (i & 31) * 4;
    int s = src[e];
    int d = dst[e];
    float v = vals[e];
    float4 hv = *(const float4*)&h[(long long)s * F_OUT + f];
    float* o = &out[(long long)d * F_OUT + f];
    atomicAdd(o + 0, v * hv.x);
    atomicAdd(o + 1, v * hv.y);
    atomicAdd(o + 2, v * hv.z);
    atomicAdd(o + 3, v * hv.w);
}

// ---------------------------------------------------------------------------
extern "C" void kernel_launch(void* const* d_in, const int* in_sizes, int n_in,
                              void* d_out, int out_size, void* d_ws, size_t ws_size,
                              hipStream_t stream)
{
    const float* x     = (const float*)d_in[0];
    const int*   esrc  = (const int*)d_in[1];
    const int*   edst  = (const int*)d_in[2];
    const float* evals = (const float*)d_in[3];
    const float* W     = (const float*)d_in[4];
    const float* bias  = (const float*)d_in[5];
    float*       out   = (float*)d_out;
    float*       h     = (float*)d_ws;   // n_nodes * F_OUT fp32 = 51.2 MB

    const int n_nodes = in_sizes[0] / F_IN;
    const int n_edges = in_sizes[1];

    // 1) dense transform
    dim3 gemm_grid((n_nodes + BM - 1) / BM);
    gemm_h_kernel<<<gemm_grid, 256, 0, stream>>>(x, W, h, n_nodes);

    // 2) bias init of output
    int total4 = n_nodes * F_OUT / 4;
    init_out_kernel<<<(total4 + 255) / 256, 256, 0, stream>>>(out, bias, total4);

    // 3) edge scatter with atomics
    int total_s = n_edges * 32;
    scatter_kernel<<<(total_s + 255) / 256, 256, 0, stream>>>(
        h, esrc, edst, evals, out, total_s);
}

// Round 2
// 531.566 us; speedup vs baseline: 5.4708x; 5.4708x over previous
//
#include <hip/hip_runtime.h>

constexpr int F_IN  = 256;
constexpr int F_OUT = 128;

#define BM 64
#define BK 32

// ---------------------------------------------------------------------------
// Stage 1: h = x @ W   (fp32, LDS-tiled, 64x128 block tile, 8x4 per thread)
// ---------------------------------------------------------------------------
__global__ __launch_bounds__(256) void gemm_h_kernel(
    const float* __restrict__ x, const float* __restrict__ W,
    float* __restrict__ h, int n_nodes)
{
    __shared__ float As[BM][BK + 4];      // 64 x 36
    __shared__ float Bs[BK][F_OUT + 4];   // 32 x 132

    const int tid  = threadIdx.x;
    const int row0 = blockIdx.x * BM;
    const int trow = tid >> 5;            // 0..7  -> 8 rows each
    const int tcol = tid & 31;            // 0..31 -> 4 cols each

    float acc[8][4];
    #pragma unroll
    for (int i = 0; i < 8; ++i)
        #pragma unroll
        for (int j = 0; j < 4; ++j) acc[i][j] = 0.f;

    const int a_r = tid >> 3;             // 0..31
    const int a_c = (tid & 7) * 4;        // 0..28
    const int b_r = tid >> 5;             // 0..7
    const int b_c = (tid & 31) * 4;       // 0..124

    for (int kt = 0; kt < F_IN; kt += BK) {
        #pragma unroll
        for (int p = 0; p < 2; ++p) {
            int r = a_r + p * 32;
            int grow = row0 + r;
            float4 v = make_float4(0.f, 0.f, 0.f, 0.f);
            if (grow < n_nodes)
                v = *(const float4*)&x[(long long)grow * F_IN + kt + a_c];
            *(float4*)&As[r][a_c] = v;
        }
        #pragma unroll
        for (int p = 0; p < 4; ++p) {
            int r = b_r + p * 8;
            float4 v = *(const float4*)&W[(kt + r) * F_OUT + b_c];
            *(float4*)&Bs[r][b_c] = v;
        }
        __syncthreads();

        #pragma unroll
        for (int k = 0; k < BK; ++k) {
            float4 b = *(float4*)&Bs[k][tcol * 4];
            #pragma unroll
            for (int i = 0; i < 8; ++i) {
                float a = As[trow * 8 + i][k];
                acc[i][0] += a * b.x;
                acc[i][1] += a * b.y;
                acc[i][2] += a * b.z;
                acc[i][3] += a * b.w;
            }
        }
        __syncthreads();
    }

    #pragma unroll
    for (int i = 0; i < 8; ++i) {
        int grow = row0 + trow * 8 + i;
        if (grow < n_nodes) {
            float4 v = make_float4(acc[i][0], acc[i][1], acc[i][2], acc[i][3]);
            *(float4*)&h[(long long)grow * F_OUT + tcol * 4] = v;
        }
    }
}

// ---------------------------------------------------------------------------
// CSR build: count -> scan -> fill
// ---------------------------------------------------------------------------
__global__ __launch_bounds__(256) void count_kernel(
    const int* __restrict__ dst, int* __restrict__ deg, int n_edges)
{
    int i = blockIdx.x * blockDim.x + threadIdx.x;
    if (i < n_edges) atomicAdd(&deg[dst[i]], 1);
}

// per-block sums over chunks of 256
__global__ __launch_bounds__(256) void sum_kernel(
    const int* __restrict__ deg, int* __restrict__ partial, int n)
{
    __shared__ int s[256];
    int t = threadIdx.x;
    int i = blockIdx.x * 256 + t;
    s[t] = (i < n) ? deg[i] : 0;
    __syncthreads();
    for (int off = 128; off > 0; off >>= 1) {
        if (t < off) s[t] += s[t + off];
        __syncthreads();
    }
    if (t == 0) partial[blockIdx.x] = s[0];
}

// single-block exclusive scan of partials (nb <= 1024)
__global__ __launch_bounds__(1024) void scan_partials_kernel(
    const int* __restrict__ partial, int* __restrict__ blockoff, int nb)
{
    __shared__ int s[1024];
    int t = threadIdx.x;
    int v = (t < nb) ? partial[t] : 0;
    s[t] = v;
    __syncthreads();
    for (int off = 1; off < 1024; off <<= 1) {
        int tmp = (t >= off) ? s[t - off] : 0;
        __syncthreads();
        s[t] += tmp;
        __syncthreads();
    }
    if (t < nb) blockoff[t] = s[t] - v;   // exclusive
}

// per-block local exclusive scan + global offset; writes offsets and cursor
__global__ __launch_bounds__(256) void local_scan_kernel(
    const int* __restrict__ deg, const int* __restrict__ blockoff,
    int* __restrict__ offsets, int* __restrict__ cursor, int n)
{
    __shared__ int s[256];
    int t = threadIdx.x;
    int i = blockIdx.x * 256 + t;
    int v = (i < n) ? deg[i] : 0;
    s[t] = v;
    __syncthreads();
    for (int off = 1; off < 256; off <<= 1) {
        int tmp = (t >= off) ? s[t - off] : 0;
        __syncthreads();
        s[t] += tmp;
        __syncthreads();
    }
    if (i < n) {
        int o = blockoff[blockIdx.x] + s[t] - v;  // exclusive
        offsets[i] = o;
        cursor[i]  = o;
    }
}

__global__ __launch_bounds__(256) void fill_kernel(
    const int* __restrict__ src, const int* __restrict__ dst,
    const float* __restrict__ vals, int* __restrict__ cursor,
    int* __restrict__ src_sorted, float* __restrict__ val_sorted, int n_edges)
{
    int e = blockIdx.x * blockDim.x + threadIdx.x;
    if (e >= n_edges) return;
    int p = atomicAdd(&cursor[dst[e]], 1);
    src_sorted[p] = src[e];
    val_sorted[p] = vals[e];
}

// ---------------------------------------------------------------------------
// Gather: one 64-lane wave per dst node, 2 features per lane (float2)
// ---------------------------------------------------------------------------
__global__ __launch_bounds__(256) void gather_kernel(
    const float* __restrict__ h, const int* __restrict__ offsets,
    const int* __restrict__ src_sorted, const float* __restrict__ val_sorted,
    const float* __restrict__ bias, float* __restrict__ out,
    int n_nodes, int n_edges)
{
    int node = blockIdx.x * 4 + (threadIdx.x >> 6);
    if (node >= n_nodes) return;
    int lane = threadIdx.x & 63;
    int f = lane * 2;

    int start = offsets[node];
    int end   = (node + 1 < n_nodes) ? offsets[node + 1] : n_edges;

    float ax = 0.f, ay = 0.f;
    int e = start;
    for (; e + 1 < end; e += 2) {
        int   s0 = src_sorted[e];
        int   s1 = src_sorted[e + 1];
        float v0 = val_sorted[e];
        float v1 = val_sorted[e + 1];
        float2 h0 = *(const float2*)&h[(long long)s0 * F_OUT + f];
        float2 h1 = *(const float2*)&h[(long long)s1 * F_OUT + f];
        ax += v0 * h0.x + v1 * h1.x;
        ay += v0 * h0.y + v1 * h1.y;
    }
    if (e < end) {
        int   s0 = src_sorted[e];
        float v0 = val_sorted[e];
        float2 h0 = *(const float2*)&h[(long long)s0 * F_OUT + f];
        ax += v0 * h0.x;
        ay += v0 * h0.y;
    }

    float2 b = *(const float2*)&bias[f];
    float2 o = make_float2(ax + b.x, ay + b.y);
    *(float2*)&out[(long long)node * F_OUT + f] = o;
}

// ---------------------------------------------------------------------------
// Fallback (round-1 path) kernels, used only if ws_size too small
// ---------------------------------------------------------------------------
__global__ void init_out_kernel(float* __restrict__ out,
                                const float* __restrict__ bias, int total4)
{
    int i = blockIdx.x * blockDim.x + threadIdx.x;
    if (i < total4) {
        int f = (i * 4) & (F_OUT - 1);
        float4 b = *(const float4*)&bias[f];
        ((float4*)out)[i] = b;
    }
}

__global__ __launch_bounds__(256) void scatter_kernel(
    const float* __restrict__ h, const int* __restrict__ src,
    const int* __restrict__ dst, const float* __restrict__ vals,
    float* __restrict__ out, int total)
{
    int i = blockIdx.x * blockDim.x + threadIdx.x;
    if (i >= total) return;
    int e = i >> 5;
    int f = (i & 31) * 4;
    int s = src[e];
    int d = dst[e];
    float v = vals[e];
    float4 hv = *(const float4*)&h[(long long)s * F_OUT + f];
    float* o = &out[(long long)d * F_OUT + f];
    atomicAdd(o + 0, v * hv.x);
    atomicAdd(o + 1, v * hv.y);
    atomicAdd(o + 2, v * hv.z);
    atomicAdd(o + 3, v * hv.w);
}

// ---------------------------------------------------------------------------
extern "C" void kernel_launch(void* const* d_in, const int* in_sizes, int n_in,
                              void* d_out, int out_size, void* d_ws, size_t ws_size,
                              hipStream_t stream)
{
    const float* x     = (const float*)d_in[0];
    const int*   esrc  = (const int*)d_in[1];
    const int*   edst  = (const int*)d_in[2];
    const float* evals = (const float*)d_in[3];
    const float* W     = (const float*)d_in[4];
    const float* bias  = (const float*)d_in[5];
    float*       out   = (float*)d_out;

    const int n_nodes = in_sizes[0] / F_IN;
    const int n_edges = in_sizes[1];
    const int nb      = (n_nodes + 255) / 256;   // scan blocks (<=1024)

    // workspace layout
    char*  base = (char*)d_ws;
    size_t off  = 0;
    float* h          = (float*)(base + off); off += (size_t)n_nodes * F_OUT * 4;
    int*   deg        = (int*)  (base + off); off += (size_t)n_nodes * 4;
    int*   offsets    = (int*)  (base + off); off += (size_t)n_nodes * 4;
    int*   cursor     = (int*)  (base + off); off += (size_t)n_nodes * 4;
    int*   partial    = (int*)  (base + off); off += (size_t)nb * 4;
    int*   blockoff   = (int*)  (base + off); off += (size_t)nb * 4;
    int*   src_sorted = (int*)  (base + off); off += (size_t)n_edges * 4;
    float* val_sorted = (float*)(base + off); off += (size_t)n_edges * 4;
    const bool csr_ok = (off <= ws_size) && (nb <= 1024);

    // 1) dense transform h = x @ W
    dim3 gemm_grid((n_nodes + BM - 1) / BM);
    gemm_h_kernel<<<gemm_grid, 256, 0, stream>>>(x, W, h, n_nodes);

    if (csr_ok) {
        // 2) CSR build
        hipMemsetAsync(deg, 0, (size_t)n_nodes * 4, stream);
        count_kernel<<<(n_edges + 255) / 256, 256, 0, stream>>>(edst, deg, n_edges);
        sum_kernel<<<nb, 256, 0, stream>>>(deg, partial, n_nodes);
        scan_partials_kernel<<<1, 1024, 0, stream>>>(partial, blockoff, nb);
        local_scan_kernel<<<nb, 256, 0, stream>>>(deg, blockoff, offsets, cursor, n_nodes);
        fill_kernel<<<(n_edges + 255) / 256, 256, 0, stream>>>(
            esrc, edst, evals, cursor, src_sorted, val_sorted, n_edges);

        // 3) gather (one wave per node), bias fused
        gather_kernel<<<(n_nodes + 3) / 4, 256, 0, stream>>>(
            h, offsets, src_sorted, val_sorted, bias, out, n_nodes, n_edges);
    } else {
        // fallback: atomic scatter (round-1 path)
        int total4 = n_nodes * F_OUT / 4;
        init_out_kernel<<<(total4 + 255) / 256, 256, 0, stream>>>(out, bias, total4);
        int total_s = n_edges * 32;
        scatter_kernel<<<(total_s + 255) / 256, 256, 0, stream>>>(
            h, esrc, edst, evals, out, total_s);
    }
}

// Round 3
// 482.694 us; speedup vs baseline: 6.0247x; 1.1012x over previous
//
#include <hip/hip_runtime.h>

constexpr int F_IN  = 256;
constexpr int F_OUT = 128;

typedef __attribute__((ext_vector_type(8))) short short8;
typedef __attribute__((ext_vector_type(4))) float f32x4;

// fp32 -> bf16 round-to-nearest-even (matches v_cvt semantics for normals)
__device__ __forceinline__ unsigned short f2bf(float f) {
    unsigned u = __float_as_uint(f);
    u += 0x7fffu + ((u >> 16) & 1u);
    return (unsigned short)(u >> 16);
}

// ---------------------------------------------------------------------------
// Prep: Wt[n][k] = bf16(W[k][n])   (tiny, one-time per launch)
// ---------------------------------------------------------------------------
__global__ void prep_wt_kernel(const float* __restrict__ W,
                               unsigned short* __restrict__ Wt)
{
    int n = blockIdx.x;      // 0..127
    int k = threadIdx.x;     // 0..255
    Wt[n * F_IN + k] = f2bf(W[k * F_OUT + n]);
}

// ---------------------------------------------------------------------------
// Stage 1: h = bf16(x @ W) via MFMA 16x16x32 bf16.
// Block = 256 thr = 4 waves; block tile M=64 (16 rows/wave), N=128 full.
// Whole Wt (bf16, 64KB) staged in LDS with +8 element row pad (2-way bank
// alias only, free). K=256 in 8 steps of 32.
// ---------------------------------------------------------------------------
#define WT_LD 264   // 256 + 8 pad; 264*2=528B row stride, 16B-aligned, stride%128B breaks bank aliasing to 2-way

__global__ __launch_bounds__(256) void gemm_mfma_kernel(
    const float* __restrict__ x, const unsigned short* __restrict__ Wt,
    unsigned short* __restrict__ h, int n_nodes)
{
    __shared__ unsigned short Bs[F_OUT * WT_LD];   // 128*264*2 = 67.6 KB

    const int tid = threadIdx.x;

    // stage Wt -> LDS (padded rows), 128 rows * 32 uint4-chunks = 4096 chunks
    {
        const uint4* src = (const uint4*)Wt;
        #pragma unroll
        for (int p = 0; p < 16; ++p) {
            int idx = p * 256 + tid;            // 0..4095
            int row = idx >> 5;                 // 0..127
            int c   = idx & 31;                 // 0..31 (16B chunks)
            *(uint4*)&Bs[row * WT_LD + c * 8] = src[idx];
        }
    }
    __syncthreads();

    const int wave = tid >> 6;
    const int lane = tid & 63;
    const int m16  = lane & 15;
    const int quad = lane >> 4;          // 0..3
    const int arow = blockIdx.x * 64 + wave * 16 + m16;
    const bool inb = arow < n_nodes;

    f32x4 acc[8];
    #pragma unroll
    for (int t = 0; t < 8; ++t) acc[t] = (f32x4)(0.f);

    #pragma unroll
    for (int ks = 0; ks < 8; ++ks) {
        const int k0 = ks * 32 + quad * 8;
        short8 afrag;
        if (inb) {
            float4 a0 = *(const float4*)&x[(long long)arow * F_IN + k0];
            float4 a1 = *(const float4*)&x[(long long)arow * F_IN + k0 + 4];
            afrag[0] = (short)f2bf(a0.x); afrag[1] = (short)f2bf(a0.y);
            afrag[2] = (short)f2bf(a0.z); afrag[3] = (short)f2bf(a0.w);
            afrag[4] = (short)f2bf(a1.x); afrag[5] = (short)f2bf(a1.y);
            afrag[6] = (short)f2bf(a1.z); afrag[7] = (short)f2bf(a1.w);
        } else {
            afrag = (short8)0;
        }
        #pragma unroll
        for (int t = 0; t < 8; ++t) {
            int n = t * 16 + m16;
            short8 bfrag = *(const short8*)&Bs[n * WT_LD + k0];
            acc[t] = __builtin_amdgcn_mfma_f32_16x16x32_bf16(afrag, bfrag, acc[t], 0, 0, 0);
        }
    }

    // D layout: col = lane&15, row = quad*4 + reg
    const int rbase = blockIdx.x * 64 + wave * 16 + quad * 4;
    #pragma unroll
    for (int r = 0; r < 4; ++r) {
        int grow = rbase + r;
        if (grow < n_nodes) {
            #pragma unroll
            for (int t = 0; t < 8; ++t)
                h[(long long)grow * F_OUT + t * 16 + m16] = f2bf(acc[t][r]);
        }
    }
}

// ---------------------------------------------------------------------------
// CSR build: count -> scan -> fill (packed src+val)
// ---------------------------------------------------------------------------
__global__ __launch_bounds__(256) void count_kernel(
    const int* __restrict__ dst, int* __restrict__ deg, int n_edges)
{
    int i = blockIdx.x * blockDim.x + threadIdx.x;
    if (i < n_edges) atomicAdd(&deg[dst[i]], 1);
}

__global__ __launch_bounds__(256) void sum_kernel(
    const int* __restrict__ deg, int* __restrict__ partial, int n)
{
    __shared__ int s[256];
    int t = threadIdx.x;
    int i = blockIdx.x * 256 + t;
    s[t] = (i < n) ? deg[i] : 0;
    __syncthreads();
    for (int off = 128; off > 0; off >>= 1) {
        if (t < off) s[t] += s[t + off];
        __syncthreads();
    }
    if (t == 0) partial[blockIdx.x] = s[0];
}

__global__ __launch_bounds__(1024) void scan_partials_kernel(
    const int* __restrict__ partial, int* __restrict__ blockoff, int nb)
{
    __shared__ int s[1024];
    int t = threadIdx.x;
    int v = (t < nb) ? partial[t] : 0;
    s[t] = v;
    __syncthreads();
    for (int off = 1; off < 1024; off <<= 1) {
        int tmp = (t >= off) ? s[t - off] : 0;
        __syncthreads();
        s[t] += tmp;
        __syncthreads();
    }
    if (t < nb) blockoff[t] = s[t] - v;
}

__global__ __launch_bounds__(256) void local_scan_kernel(
    const int* __restrict__ deg, const int* __restrict__ blockoff,
    int* __restrict__ offsets, int* __restrict__ cursor, int n)
{
    __shared__ int s[256];
    int t = threadIdx.x;
    int i = blockIdx.x * 256 + t;
    int v = (i < n) ? deg[i] : 0;
    s[t] = v;
    __syncthreads();
    for (int off = 1; off < 256; off <<= 1) {
        int tmp = (t >= off) ? s[t - off] : 0;
        __syncthreads();
        s[t] += tmp;
        __syncthreads();
    }
    if (i < n) {
        int o = blockoff[blockIdx.x] + s[t] - v;
        offsets[i] = o;
        cursor[i]  = o;
    }
}

__global__ __launch_bounds__(256) void fill_kernel(
    const int* __restrict__ src, const int* __restrict__ dst,
    const float* __restrict__ vals, int* __restrict__ cursor,
    uint2* __restrict__ sv_sorted, int n_edges)
{
    int e = blockIdx.x * blockDim.x + threadIdx.x;
    if (e >= n_edges) return;
    int p = atomicAdd(&cursor[dst[e]], 1);
    sv_sorted[p] = make_uint2((unsigned)src[e], __float_as_uint(vals[e]));
}

// ---------------------------------------------------------------------------
// Gather: one wave per dst node, 2 bf16 features per lane (4B load/row)
// ---------------------------------------------------------------------------
__global__ __launch_bounds__(256) void gather_kernel(
    const unsigned short* __restrict__ h, const int* __restrict__ offsets,
    const uint2* __restrict__ sv, const float* __restrict__ bias,
    float* __restrict__ out, int n_nodes, int n_edges)
{
    int node = blockIdx.x * 4 + (threadIdx.x >> 6);
    if (node >= n_nodes) return;
    int lane = threadIdx.x & 63;
    int f = lane * 2;

    int start = offsets[node];
    int end   = (node + 1 < n_nodes) ? offsets[node + 1] : n_edges;

    float ax = 0.f, ay = 0.f;
    int e = start;
    for (; e + 1 < end; e += 2) {
        uint2 p0 = sv[e];
        uint2 p1 = sv[e + 1];
        unsigned u0 = *(const unsigned*)&h[(long long)p0.x * F_OUT + f];
        unsigned u1 = *(const unsigned*)&h[(long long)p1.x * F_OUT + f];
        float v0 = __uint_as_float(p0.y);
        float v1 = __uint_as_float(p1.y);
        ax += v0 * __uint_as_float(u0 << 16) + v1 * __uint_as_float(u1 << 16);
        ay += v0 * __uint_as_float(u0 & 0xffff0000u)
            + v1 * __uint_as_float(u1 & 0xffff0000u);
    }
    if (e < end) {
        uint2 p0 = sv[e];
        unsigned u0 = *(const unsigned*)&h[(long long)p0.x * F_OUT + f];
        float v0 = __uint_as_float(p0.y);
        ax += v0 * __uint_as_float(u0 << 16);
        ay += v0 * __uint_as_float(u0 & 0xffff0000u);
    }

    float2 b = *(const float2*)&bias[f];
    *(float2*)&out[(long long)node * F_OUT + f] = make_float2(ax + b.x, ay + b.y);
}

// ---------------------------------------------------------------------------
extern "C" void kernel_launch(void* const* d_in, const int* in_sizes, int n_in,
                              void* d_out, int out_size, void* d_ws, size_t ws_size,
                              hipStream_t stream)
{
    const float* x     = (const float*)d_in[0];
    const int*   esrc  = (const int*)d_in[1];
    const int*   edst  = (const int*)d_in[2];
    const float* evals = (const float*)d_in[3];
    const float* W     = (const float*)d_in[4];
    const float* bias  = (const float*)d_in[5];
    float*       out   = (float*)d_out;

    const int n_nodes = in_sizes[0] / F_IN;
    const int n_edges = in_sizes[1];
    const int nb      = (n_nodes + 255) / 256;

    auto align16 = [](size_t v) { return (v + 15) & ~(size_t)15; };
    char*  base = (char*)d_ws;
    size_t off  = 0;
    unsigned short* h  = (unsigned short*)(base + off); off = align16(off + (size_t)n_nodes * F_OUT * 2);
    unsigned short* Wt = (unsigned short*)(base + off); off = align16(off + (size_t)F_IN * F_OUT * 2);
    int*   deg        = (int*)(base + off);  off = align16(off + (size_t)n_nodes * 4);
    int*   offsets    = (int*)(base + off);  off = align16(off + (size_t)n_nodes * 4);
    int*   cursor     = (int*)(base + off);  off = align16(off + (size_t)n_nodes * 4);
    int*   partial    = (int*)(base + off);  off = align16(off + (size_t)nb * 4);
    int*   blockoff   = (int*)(base + off);  off = align16(off + (size_t)nb * 4);
    uint2* sv_sorted  = (uint2*)(base + off); off = align16(off + (size_t)n_edges * 8);
    (void)ws_size;

    // 1) W^T -> bf16, then h = bf16(x @ W) via MFMA
    prep_wt_kernel<<<F_OUT, F_IN, 0, stream>>>(W, Wt);
    gemm_mfma_kernel<<<(n_nodes + 63) / 64, 256, 0, stream>>>(x, Wt, h, n_nodes);

    // 2) CSR build
    hipMemsetAsync(deg, 0, (size_t)n_nodes * 4, stream);
    count_kernel<<<(n_edges + 255) / 256, 256, 0, stream>>>(edst, deg, n_edges);
    sum_kernel<<<nb, 256, 0, stream>>>(deg, partial, n_nodes);
    scan_partials_kernel<<<1, 1024, 0, stream>>>(partial, blockoff, nb);
    local_scan_kernel<<<nb, 256, 0, stream>>>(deg, blockoff, offsets, cursor, n_nodes);
    fill_kernel<<<(n_edges + 255) / 256, 256, 0, stream>>>(
        esrc, edst, evals, cursor, sv_sorted, n_edges);

    // 3) gather (one wave per node), bias fused
    gather_kernel<<<(n_nodes + 3) / 4, 256, 0, stream>>>(
        h, offsets, sv_sorted, bias, out, n_nodes, n_edges);
}